// Round 4
// baseline (299.718 us; speedup 1.0000x reference)
//
#include <hip/hip_runtime.h>

namespace {

constexpr int B  = 16;
constexpr int D  = 128;
constexpr int C  = 6;
constexpr int H  = 128;
constexpr int W  = 128;
constexpr int HWC = H * W;          // 16384
constexpr int HO = 512, WO = 512;   // 4x upsample

// ---------------------------------------------------------------------------
// k_fused: ONE HBM pass over assp, zero __syncthreads on the data path.
// Phase A (lane = pixel): stream assp[b,:,px] coalesced (256B/instr/wave),
//   6 register dots, argmax class (first-wins == jnp.argmax), write
//   x = dot/12 + bias, per-wave ballot counts -> 6 atomics.
// Phase B (lane = d-row pair): the wave's 64px x 128d = 32KB working set is
//   exactly what THIS wave streamed in phase A -> L2/L3-hot. Lane walks rows
//   d=lane, d=lane+64 in float4 steps; cls(px) comes from __shfl -> wave-
//   uniform scalar -> the 6-way class select runs on the scalar pipe.
// Epilogue: 12KB LDS reduce across the block's 4 waves, 768 atomics/block.
// ---------------------------------------------------------------------------
__global__ __launch_bounds__(256) void k_fused(const float* __restrict__ assp,
                                               const float* __restrict__ cls_w,
                                               const float* __restrict__ cls_b,
                                               float* __restrict__ sums,
                                               int* __restrict__ counts,
                                               float* __restrict__ x) {
  __shared__ float part[4 * C * D];   // part[w][c][d], 12 KB

  const int t    = threadIdx.x;
  const int b    = blockIdx.y;
  const int lane = t & 63;
  const int wv   = t >> 6;
  const int px   = blockIdx.x * 256 + t;         // phase-A pixel
  const int px0  = blockIdx.x * 256 + wv * 64;   // wave's pixel base

  // ---- phase A: px-ownership stream ----
  const float* col = assp + ((size_t)b * D) * HWC + px;
  float a[C] = {0.f, 0.f, 0.f, 0.f, 0.f, 0.f};
#pragma unroll 8
  for (int d = 0; d < D; ++d) {
    float vv = col[(size_t)d * HWC];
#pragma unroll
    for (int c = 0; c < C; ++c) a[c] += vv * cls_w[c * D + d];
  }

  // argmax, first-wins ties == jnp.argmax
  float bv = a[0] + cls_b[0];
  int cls = 0;
#pragma unroll
  for (int c = 1; c < C; ++c) {
    float pv = a[c] + cls_b[c];
    if (pv > bv) { bv = pv; cls = c; }
  }

  // x = pseudo/12 + bias  (softmax(...,axis=1).mean(axis=1) == 1/12)
  const float inv12 = 1.0f / 12.0f;
  float* xb = x + ((size_t)b * C) * HWC + px;
#pragma unroll
  for (int c = 0; c < C; ++c) xb[(size_t)c * HWC] = a[c] * inv12 + cls_b[c];

  // per-wave counts: 6 ballots, 6 atomics
  int cnt = 0;
#pragma unroll
  for (int c = 0; c < C; ++c) {
    unsigned long long m = __ballot(cls == c);
    if (lane == c) cnt = (int)__popcll(m);
  }
  if (lane < C) atomicAdd(&counts[b * C + lane], cnt);

  // ---- phase B: d-ownership over the wave's own (cache-hot) 32 KB ----
  const float* row0 = assp + ((size_t)b * D + lane) * HWC + px0;
  const float* row1 = assp + ((size_t)b * D + lane + 64) * HWC + px0;
  float acc0[C] = {0.f, 0.f, 0.f, 0.f, 0.f, 0.f};
  float acc1[C] = {0.f, 0.f, 0.f, 0.f, 0.f, 0.f};
#pragma unroll
  for (int g = 0; g < 16; ++g) {
    float4 u  = *(const float4*)(row0 + 4 * g);
    float4 w4 = *(const float4*)(row1 + 4 * g);
#pragma unroll
    for (int j = 0; j < 4; ++j) {
      int cj = __shfl(cls, 4 * g + j, 64);   // wave-uniform scalar
      float uj = (&u.x)[j];                  // j is compile-time (unrolled)
      float wj = (&w4.x)[j];
#pragma unroll
      for (int cc = 0; cc < C; ++cc)
        if (cj == cc) { acc0[cc] += uj; acc1[cc] += wj; }  // uniform branch
    }
  }

  // ---- epilogue: block reduce (4 waves) + one atomic burst ----
#pragma unroll
  for (int cc = 0; cc < C; ++cc) {
    part[(wv * C + cc) * D + lane]      = acc0[cc];
    part[(wv * C + cc) * D + lane + 64] = acc1[cc];
  }
  __syncthreads();
  for (int i = t; i < C * D; i += 256) {
    float s = part[0 * C * D + i] + part[1 * C * D + i]
            + part[2 * C * D + i] + part[3 * C * D + i];
    atomicAdd(&sums[(size_t)b * C * D + i], s);
  }
}

// ---------------------------------------------------------------------------
// K3: per dropped pixel: protoC on the fly from sums/counts, nearest proto
// (first-wins argmin == over the 12=2x6 duplicated list), patch x directly.
// one wave per (b,p); lane owns d and d+64
// ---------------------------------------------------------------------------
__global__ void k_patch(const float* __restrict__ assp,
                        const float* __restrict__ sums,
                        const int* __restrict__ counts,
                        const float* __restrict__ cls_w,
                        const float* __restrict__ cls_b,
                        const int* __restrict__ px,
                        const int* __restrict__ py,
                        int P,
                        float* __restrict__ x) {
  int bp = blockIdx.x;
  int b = bp / P, p = bp % P;
  int hw = px[p] * W + py[p];
  int lane = threadIdx.x;                  // 64 threads = 1 wave
  const float* fbase = assp + ((size_t)b * D) * HWC + hw;

  float f0 = fbase[(size_t)lane * HWC];
  float f1 = fbase[(size_t)(lane + 64) * HWC];

  float pv0[C], pv1[C], ds[C];
#pragma unroll
  for (int c = 0; c < C; ++c) {
    float cnt = (float)counts[b * C + c];
    float s0 = sums[((size_t)b * C + c) * D + lane];
    float s1 = sums[((size_t)b * C + c) * D + lane + 64];
    float q0 = (cnt > 0.f) ? s0 / (cnt + 1e-5f) : 0.f;
    float q1 = (cnt > 0.f) ? s1 / (cnt + 1e-5f) : 0.f;
    pv0[c] = q0; pv1[c] = q1;
    float e0 = q0 - f0, e1 = q1 - f1;
    float tt = e0 * e0 + e1 * e1;
#pragma unroll
    for (int off = 32; off >= 1; off >>= 1) tt += __shfl_xor(tt, off, 64);
    ds[c] = tt;                            // identical on all lanes
  }
  int best = 0; float bv = ds[0];          // first-wins ties == jnp.argmin
#pragma unroll
  for (int c = 1; c < C; ++c)
    if (ds[c] < bv) { bv = ds[c]; best = c; }

  float v0 = 0.f, v1 = 0.f;                // select without dynamic indexing
#pragma unroll
  for (int c = 0; c < C; ++c) {
    if (best == c) { v0 = pv0[c]; v1 = pv1[c]; }
  }

  float myx = 0.f;
#pragma unroll
  for (int c = 0; c < C; ++c) {
    float tt = v0 * cls_w[c * D + lane] + v1 * cls_w[c * D + lane + 64];
#pragma unroll
    for (int off = 32; off >= 1; off >>= 1) tt += __shfl_xor(tt, off, 64);
    float val = tt * (1.0f / 12.0f) + cls_b[c];
    if (lane == c) myx = val;
  }
  if (lane < C) x[((size_t)b * C + lane) * HWC + hw] = myx;
}

// ---------------------------------------------------------------------------
// K4: bilinear 4x upsample. Weights via exact integer math; <=3 input rows
// staged in LDS; 2 output rows per block; float4 coalesced stores.
// ---------------------------------------------------------------------------
__global__ __launch_bounds__(256) void k_up(const float* __restrict__ x,
                                            float* __restrict__ out) {
  __shared__ float rows[3 * W];            // 1.5 KB

  const int t = threadIdx.x;
  const size_t base = (size_t)blockIdx.x * 1024;   // first linear output index
  const int bc = (int)(base >> 18);                // output image (b*C+c)
  const int Y0 = ((int)(base >> 9)) & (HO - 1);    // first of 2 output rows

  const int ry = (Y0 * (H - 1)) / (HO - 1);        // lowest needed input row

  if (t < 96) {
    int r  = t >> 5;                               // 0..2
    int xx = (t & 31) * 4;
    int rr = ry + r; if (rr > H - 1) rr = H - 1;
    *(float4*)&rows[r * W + xx] =
        *(const float4*)(x + (size_t)bc * HWC + (size_t)rr * W + xx);
  }
  __syncthreads();

  const int h  = t >> 7;                           // which output row
  const int tt = t & 127;                          // 4 consecutive X each
  const int Y  = Y0 + h;

  const int ynum = Y * (H - 1);
  const int yl   = ynum / (HO - 1);
  const float wy = (float)((double)(ynum - yl * (HO - 1)) * (1.0 / (HO - 1)));
  int yh = yl + 1; if (yh > H - 1) yh = H - 1;
  const float* r0 = &rows[(yl - ry) * W];
  const float* r1 = &rows[(yh - ry) * W];

  float o[4];
#pragma unroll
  for (int j = 0; j < 4; ++j) {
    int X   = 4 * tt + j;
    int num = X * (W - 1);
    int lo  = num / (WO - 1);
    float wx = (float)((double)(num - lo * (WO - 1)) * (1.0 / (WO - 1)));
    int hi = lo + 1; if (hi > W - 1) hi = W - 1;

    float v00 = r0[lo], v01 = r0[hi], v10 = r1[lo], v11 = r1[hi];
    o[j] = (1.f - wy) * ((1.f - wx) * v00 + wx * v01)
         +        wy  * ((1.f - wx) * v10 + wx * v11);
  }
  float4 o4 = {o[0], o[1], o[2], o[3]};
  *(float4*)(out + base + (size_t)h * WO + 4 * tt) = o4;
}

} // namespace

extern "C" void kernel_launch(void* const* d_in, const int* in_sizes, int n_in,
                              void* d_out, int out_size, void* d_ws, size_t ws_size,
                              hipStream_t stream) {
  // inputs: assp, cls_w, cls_b, key_w, key_b, query_w, query_b, px, py
  const float* assp  = (const float*)d_in[0];
  const float* cls_w = (const float*)d_in[1];
  const float* cls_b = (const float*)d_in[2];
  const int*   px    = (const int*)d_in[7];
  const int*   py    = (const int*)d_in[8];
  const int    P     = in_sizes[7];             // 102

  // workspace layout
  char* ws = (char*)d_ws;
  float* sums   = (float*)ws;                   // B*C*D = 49152 B
  int*   counts = (int*)(ws + 49152);           // B*C*4 = 384 B
  float* x      = (float*)(ws + 65536);         // B*C*HWC*4 = 6 MB

  float* out = (float*)d_out;

  hipMemsetAsync(ws, 0, 49152 + 384, stream);
  k_fused<<<dim3(HWC / 256, B), 256, 0, stream>>>(assp, cls_w, cls_b, sums, counts, x);
  k_patch<<<B * P, 64, 0, stream>>>(assp, sums, counts, cls_w, cls_b, px, py, P, x);
  k_up<<<(B * C * HO * WO) / 1024, 256, 0, stream>>>(x, out);
}